// Round 1
// baseline (945.372 us; speedup 1.0000x reference)
//
#include <hip/hip_runtime.h>

#define NP 32
#define NROWS 65536

#if __has_builtin(__builtin_amdgcn_rcpf)
#define FAST_RCP(x) __builtin_amdgcn_rcpf(x)
#else
#define FAST_RCP(x) (1.0f / (x))
#endif

__device__ __forceinline__ float fast_tanh(float v) {
    // tanh(x) = (e^{2x}-1)/(e^{2x}+1); clamp so exp can't overflow.
    float xc = fminf(fmaxf(v, -9.0f), 9.0f);
    float e = __expf(2.0f * xc);            // v_exp_f32 path
    return (e - 1.0f) * FAST_RCP(e + 1.0f); // v_rcp_f32, ~1ulp approx
}

// ACT: 0 = none, 1 = relu, 2 = tanh. Fully unrolled so hin/hout stay in VGPRs
// and weight offsets are compile-time constants off a block-uniform base
// (=> scalar s_load, FMAs read the weight from an SGPR operand).
template <int IN, int OUT, int ACT>
__device__ __forceinline__ void layer(const float* __restrict__ W,
                                      const float* __restrict__ b,
                                      const float* hin, float* hout) {
#pragma unroll
    for (int o = 0; o < OUT; ++o) {
        float t = b[o];
#pragma unroll
        for (int i = 0; i < IN; ++i) t = fmaf(W[o * IN + i], hin[i], t);
        if (ACT == 1) t = fmaxf(t, 0.0f);
        else if (ACT == 2) t = fast_tanh(t);
        hout[o] = t;
    }
}

__global__ __launch_bounds__(256) void fused_mlp(
    const float* __restrict__ x,
    const float* __restrict__ Wa1, const float* __restrict__ ba1,
    const float* __restrict__ Wa2, const float* __restrict__ ba2,
    const float* __restrict__ Wa3, const float* __restrict__ ba3,
    const float* __restrict__ Wa4, const float* __restrict__ ba4,
    const float* __restrict__ Wa5, const float* __restrict__ ba5,
    const float* __restrict__ Wb1, const float* __restrict__ bb1,
    const float* __restrict__ Wb2, const float* __restrict__ bb2,
    const float* __restrict__ Wb3, const float* __restrict__ bb3,
    const float* __restrict__ Wb4, const float* __restrict__ bb4,
    const float* __restrict__ Wb5, const float* __restrict__ bb5,
    const float* __restrict__ Wb6, const float* __restrict__ bb6,
    float* __restrict__ out) {
    const int p = blockIdx.y;                       // feature index (uniform)
    const int n = blockIdx.x * 256 + threadIdx.x;   // row index
    const int row = n * NP;

    // ---------------- Encoder B (leave-one-out, 31->64->32->32->16->8->1) ---
    // Static register indices; the skip-p is runtime ADDRESS math only.
    float xb[NP - 1];
#pragma unroll
    for (int f = 0; f < NP - 1; ++f)
        xb[f] = x[row + f + (f >= p ? 1 : 0)];

    float g1[64];
    layer<31, 64, 1>(Wb1 + p * (64 * 31), bb1 + p * 64, xb, g1);
    float g2[32];
    layer<64, 32, 2>(Wb2 + p * (32 * 64), bb2 + p * 32, g1, g2);
    float g3[32];
    layer<32, 32, 2>(Wb3 + p * (32 * 32), bb3 + p * 32, g2, g3);
    float g4[16];
    layer<32, 16, 2>(Wb4 + p * (16 * 32), bb4 + p * 16, g3, g4);
    float g5[8];
    layer<16, 8, 0>(Wb5 + p * (8 * 16), bb5 + p * 8, g4, g5);
    float bv;
    layer<8, 1, 0>(Wb6 + p * 8, bb6 + p, g5, &bv);

    // ---------------- Encoder A (scalar input, 1->64->32->16->8->1) ---------
    float xa = x[row + p];
    float h1[64];
    {
        const float* w = Wa1 + p * 64;   // [64,1] weights
        const float* bb = ba1 + p * 64;
#pragma unroll
        for (int o = 0; o < 64; ++o)
            h1[o] = fmaxf(fmaf(w[o], xa, bb[o]), 0.0f);
    }
    float h2[32];
    layer<64, 32, 2>(Wa2 + p * (32 * 64), ba2 + p * 32, h1, h2);
    float h3[16];
    layer<32, 16, 2>(Wa3 + p * (16 * 32), ba3 + p * 16, h2, h3);
    float h4[8];
    layer<16, 8, 2>(Wa4 + p * (8 * 16), ba4 + p * 8, h3, h4);
    float av;
    layer<8, 1, 0>(Wa5 + p * 8, ba5 + p, h4, &av);

    // out[n, 2p] = a, out[n, 2p+1] = b  -> one aligned float2 store
    reinterpret_cast<float2*>(out)[n * NP + p] = make_float2(av, bv);
}

extern "C" void kernel_launch(void* const* d_in, const int* in_sizes, int n_in,
                              void* d_out, int out_size, void* d_ws,
                              size_t ws_size, hipStream_t stream) {
    const float* x   = (const float*)d_in[0];
    const float* Wa1 = (const float*)d_in[1];
    const float* ba1 = (const float*)d_in[2];
    const float* Wa2 = (const float*)d_in[3];
    const float* ba2 = (const float*)d_in[4];
    const float* Wa3 = (const float*)d_in[5];
    const float* ba3 = (const float*)d_in[6];
    const float* Wa4 = (const float*)d_in[7];
    const float* ba4 = (const float*)d_in[8];
    const float* Wa5 = (const float*)d_in[9];
    const float* ba5 = (const float*)d_in[10];
    const float* Wb1 = (const float*)d_in[11];
    const float* bb1 = (const float*)d_in[12];
    const float* Wb2 = (const float*)d_in[13];
    const float* bb2 = (const float*)d_in[14];
    const float* Wb3 = (const float*)d_in[15];
    const float* bb3 = (const float*)d_in[16];
    const float* Wb4 = (const float*)d_in[17];
    const float* bb4 = (const float*)d_in[18];
    const float* Wb5 = (const float*)d_in[19];
    const float* bb5 = (const float*)d_in[20];
    const float* Wb6 = (const float*)d_in[21];
    const float* bb6 = (const float*)d_in[22];

    dim3 grid(NROWS / 256, NP);
    fused_mlp<<<grid, 256, 0, stream>>>(
        x, Wa1, ba1, Wa2, ba2, Wa3, ba3, Wa4, ba4, Wa5, ba5,
        Wb1, bb1, Wb2, bb2, Wb3, bb3, Wb4, bb4, Wb5, bb5, Wb6, bb6,
        (float*)d_out);
}

// Round 2
// 919.358 us; speedup vs baseline: 1.0283x; 1.0283x over previous
//
#include <hip/hip_runtime.h>

#define NP 32
#define NROWS 65536

#if __has_builtin(__builtin_amdgcn_rcpf)
#define FAST_RCP(x) __builtin_amdgcn_rcpf(x)
#else
#define FAST_RCP(x) (1.0f / (x))
#endif

__device__ __forceinline__ float fast_tanh(float v) {
    // tanh(x) = (e^{2x}-1)/(e^{2x}+1); clamp so exp can't overflow.
    float xc = fminf(fmaxf(v, -9.0f), 9.0f);
    float e = __expf(2.0f * xc);            // v_exp_f32 path
    return (e - 1.0f) * FAST_RCP(e + 1.0f); // v_rcp_f32, ~1ulp approx
}

// ACT: 0 = none, 1 = relu, 2 = tanh. Fully unrolled: hin/hout stay in VGPRs,
// weight addresses are block-uniform (scalar s_load path), FMA reads the
// weight as the single allowed SGPR operand.
template <int IN, int OUT, int ACT>
__device__ __forceinline__ void layer(const float* __restrict__ W,
                                      const float* __restrict__ b,
                                      const float* __restrict__ hin,
                                      float* __restrict__ hout) {
#pragma unroll
    for (int o = 0; o < OUT; ++o) {
        float t = b[o];
#pragma unroll
        for (int i = 0; i < IN; ++i) t = fmaf(W[o * IN + i], hin[i], t);
        if (ACT == 1) t = fmaxf(t, 0.0f);
        else if (ACT == 2) t = fast_tanh(t);
        hout[o] = t;
    }
}

// min 3 waves/EU -> VGPR cap ~170. Peak live set is ~110 floats
// (g1[64]+g2[32]+temps); round-1's default heuristic capped at 68 VGPRs and
// spilled ~50 MB of hidden state to scratch (WRITE_SIZE 69 MB vs 16.7 ideal).
__global__ __launch_bounds__(256, 3) void fused_mlp(
    const float* __restrict__ x,
    const float* __restrict__ Wa1, const float* __restrict__ ba1,
    const float* __restrict__ Wa2, const float* __restrict__ ba2,
    const float* __restrict__ Wa3, const float* __restrict__ ba3,
    const float* __restrict__ Wa4, const float* __restrict__ ba4,
    const float* __restrict__ Wa5, const float* __restrict__ ba5,
    const float* __restrict__ Wb1, const float* __restrict__ bb1,
    const float* __restrict__ Wb2, const float* __restrict__ bb2,
    const float* __restrict__ Wb3, const float* __restrict__ bb3,
    const float* __restrict__ Wb4, const float* __restrict__ bb4,
    const float* __restrict__ Wb5, const float* __restrict__ bb5,
    const float* __restrict__ Wb6, const float* __restrict__ bb6,
    float* __restrict__ out) {
    const int p = blockIdx.y;                       // feature index (uniform)
    const int n = blockIdx.x * 256 + threadIdx.x;   // row index

    // ---- load the full 32-float row as 8 aligned float4 (128 B/lane) ------
    const float4* xrow = reinterpret_cast<const float4*>(x + n * NP);
    float4 r[8];
#pragma unroll
    for (int q = 0; q < 8; ++q) r[q] = xrow[q];
    const float* rf = reinterpret_cast<const float*>(r);

    // leave-one-out select: condition (f < p) is block-uniform -> cheap
    float xb[NP - 1];
#pragma unroll
    for (int f = 0; f < NP - 1; ++f)
        xb[f] = (f < p) ? rf[f] : rf[f + 1];
    float xa = rf[0];   // placeholder; replaced by select below
    {
        // xa = rf[p] without runtime indexing (avoid scratch): uniform selects
        float t = rf[0];
#pragma unroll
        for (int f = 1; f < NP; ++f) t = (p == f) ? rf[f] : t;
        xa = t;
    }

    // ---------------- Encoder B (leave-one-out, 31->64->32->32->16->8->1) ---
    float g1[64];
    layer<31, 64, 1>(Wb1 + p * (64 * 31), bb1 + p * 64, xb, g1);
    float g2[32];
    layer<64, 32, 2>(Wb2 + p * (32 * 64), bb2 + p * 32, g1, g2);
    float g3[32];
    layer<32, 32, 2>(Wb3 + p * (32 * 32), bb3 + p * 32, g2, g3);
    float g4[16];
    layer<32, 16, 2>(Wb4 + p * (16 * 32), bb4 + p * 16, g3, g4);
    float g5[8];
    layer<16, 8, 0>(Wb5 + p * (8 * 16), bb5 + p * 8, g4, g5);
    float bv;
    layer<8, 1, 0>(Wb6 + p * 8, bb6 + p, g5, &bv);

    // ---------------- Encoder A (scalar input, 1->64->32->16->8->1) ---------
    float h1[64];
    {
        const float* w = Wa1 + p * 64;   // [64,1] weights
        const float* bb = ba1 + p * 64;
#pragma unroll
        for (int o = 0; o < 64; ++o)
            h1[o] = fmaxf(fmaf(w[o], xa, bb[o]), 0.0f);
    }
    float h2[32];
    layer<64, 32, 2>(Wa2 + p * (32 * 64), ba2 + p * 32, h1, h2);
    float h3[16];
    layer<32, 16, 2>(Wa3 + p * (16 * 32), ba3 + p * 16, h2, h3);
    float h4[8];
    layer<16, 8, 2>(Wa4 + p * (8 * 16), ba4 + p * 8, h3, h4);
    float av;
    layer<8, 1, 0>(Wa5 + p * 8, ba5 + p, h4, &av);

    // out[n, 2p] = a, out[n, 2p+1] = b  -> one aligned float2 store
    reinterpret_cast<float2*>(out)[n * NP + p] = make_float2(av, bv);
}

extern "C" void kernel_launch(void* const* d_in, const int* in_sizes, int n_in,
                              void* d_out, int out_size, void* d_ws,
                              size_t ws_size, hipStream_t stream) {
    const float* x   = (const float*)d_in[0];
    const float* Wa1 = (const float*)d_in[1];
    const float* ba1 = (const float*)d_in[2];
    const float* Wa2 = (const float*)d_in[3];
    const float* ba2 = (const float*)d_in[4];
    const float* Wa3 = (const float*)d_in[5];
    const float* ba3 = (const float*)d_in[6];
    const float* Wa4 = (const float*)d_in[7];
    const float* ba4 = (const float*)d_in[8];
    const float* Wa5 = (const float*)d_in[9];
    const float* ba5 = (const float*)d_in[10];
    const float* Wb1 = (const float*)d_in[11];
    const float* bb1 = (const float*)d_in[12];
    const float* Wb2 = (const float*)d_in[13];
    const float* bb2 = (const float*)d_in[14];
    const float* Wb3 = (const float*)d_in[15];
    const float* bb3 = (const float*)d_in[16];
    const float* Wb4 = (const float*)d_in[17];
    const float* bb4 = (const float*)d_in[18];
    const float* Wb5 = (const float*)d_in[19];
    const float* bb5 = (const float*)d_in[20];
    const float* Wb6 = (const float*)d_in[21];
    const float* bb6 = (const float*)d_in[22];

    dim3 grid(NROWS / 256, NP);
    fused_mlp<<<grid, 256, 0, stream>>>(
        x, Wa1, ba1, Wa2, ba2, Wa3, ba3, Wa4, ba4, Wa5, ba5,
        Wb1, bb1, Wb2, bb2, Wb3, bb3, Wb4, bb4, Wb5, bb5, Wb6, bb6,
        (float*)d_out);
}

// Round 3
// 831.287 us; speedup vs baseline: 1.1372x; 1.1059x over previous
//
#include <hip/hip_runtime.h>

#define NP 32
#define NROWS 65536

#if __has_builtin(__builtin_amdgcn_rcpf)
#define FAST_RCP(x) __builtin_amdgcn_rcpf(x)
#else
#define FAST_RCP(x) (1.0f / (x))
#endif

__device__ __forceinline__ float fast_tanh(float v) {
    // tanh(x) = (e^{2x}-1)/(e^{2x}+1); clamp so exp can't overflow.
    float xc = fminf(fmaxf(v, -9.0f), 9.0f);
    float e = __expf(2.0f * xc);            // v_exp_f32 path
    return (e - 1.0f) * FAST_RCP(e + 1.0f); // v_rcp_f32
}

// Fused layer pair with the MIDDLE dimension chunked by CH:
//   mid = act1(W1 . hin + b1)        (IN -> NCH*CH)
//   acc = W2 . mid + b2              (NCH*CH -> OUT), caller applies act2
// Register-residency guarantee: the chunk loop variable `c` appears ONLY in
// pointer arithmetic (uniform scalar-load addresses). Register arrays (hin,
// m, acc) are indexed exclusively by fully-unrolled small loops, so SROA
// promotion cannot fail regardless of whether the c-loop unrolls. Round 1/2
// failure mode: #pragma unroll on a 2048-FMA body silently stayed rolled ->
// hout[o] runtime-indexed -> whole array in scratch (VGPR=68, 52 MB spill).
template <int IN, int NCH, int CH, int OUT, bool RELU_MID>
__device__ __forceinline__ void fused2(const float* __restrict__ W1,
                                       const float* __restrict__ b1,
                                       const float* __restrict__ W2,
                                       const float* __restrict__ b2,
                                       const float* __restrict__ hin,
                                       float* __restrict__ acc) {
#pragma unroll
    for (int o = 0; o < OUT; ++o) acc[o] = b2[o];
    for (int c = 0; c < NCH; ++c) {   // rolled OK: c never indexes a reg array
        float m[CH];
#pragma unroll
        for (int j = 0; j < CH; ++j) {
            const float* w = W1 + (c * CH + j) * IN;
            float s = b1[c * CH + j];
#pragma unroll
            for (int i = 0; i < IN; ++i) s = fmaf(w[i], hin[i], s);
            m[j] = RELU_MID ? fmaxf(s, 0.0f) : fast_tanh(s);
        }
#pragma unroll
        for (int o = 0; o < OUT; ++o) {
            const float* w2 = W2 + o * (NCH * CH) + c * CH;
            float a = acc[o];
#pragma unroll
            for (int j = 0; j < CH; ++j) a = fmaf(w2[j], m[j], a);
            acc[o] = a;
        }
    }
}

// Peak live set ~75 floats -> fits 128 VGPRs; 4 waves/EU (16 waves/CU).
__global__ __launch_bounds__(256, 4) void fused_mlp(
    const float* __restrict__ x,
    const float* __restrict__ Wa1, const float* __restrict__ ba1,
    const float* __restrict__ Wa2, const float* __restrict__ ba2,
    const float* __restrict__ Wa3, const float* __restrict__ ba3,
    const float* __restrict__ Wa4, const float* __restrict__ ba4,
    const float* __restrict__ Wa5, const float* __restrict__ ba5,
    const float* __restrict__ Wb1, const float* __restrict__ bb1,
    const float* __restrict__ Wb2, const float* __restrict__ bb2,
    const float* __restrict__ Wb3, const float* __restrict__ bb3,
    const float* __restrict__ Wb4, const float* __restrict__ bb4,
    const float* __restrict__ Wb5, const float* __restrict__ bb5,
    const float* __restrict__ Wb6, const float* __restrict__ bb6,
    float* __restrict__ out) {
    const int p = blockIdx.y;                       // feature index (uniform)
    const int n = blockIdx.x * 256 + threadIdx.x;   // row index

    // ---- full 32-float row via 8 aligned float4 loads --------------------
    const float4* xrow = reinterpret_cast<const float4*>(x + n * NP);
    float4 r[8];
#pragma unroll
    for (int q = 0; q < 8; ++q) r[q] = xrow[q];
    const float* rf = reinterpret_cast<const float*>(r);

    // leave-one-out gather; (f < p) is block-uniform
    float xb[NP - 1];
#pragma unroll
    for (int f = 0; f < NP - 1; ++f)
        xb[f] = (f < p) ? rf[f] : rf[f + 1];
    const float xa = x[n * NP + p];   // one extra scalar load, L1-hot

    // ================= Encoder B: 31 ->[64]-> 32 ->[32]-> 16 -> 8 -> 1 =====
    float g2[32];
    fused2<31, 8, 8, 32, true>(Wb1 + p * (64 * 31), bb1 + p * 64,
                               Wb2 + p * (32 * 64), bb2 + p * 32, xb, g2);
#pragma unroll
    for (int o = 0; o < 32; ++o) g2[o] = fast_tanh(g2[o]);

    float g4[16];
    fused2<32, 4, 8, 16, false>(Wb3 + p * (32 * 32), bb3 + p * 32,
                                Wb4 + p * (16 * 32), bb4 + p * 16, g2, g4);
#pragma unroll
    for (int o = 0; o < 16; ++o) g4[o] = fast_tanh(g4[o]);

    float g5[8];
    {
        const float* W = Wb5 + p * (8 * 16);
        const float* b = bb5 + p * 8;
#pragma unroll
        for (int o = 0; o < 8; ++o) {
            float s = b[o];
#pragma unroll
            for (int i = 0; i < 16; ++i) s = fmaf(W[o * 16 + i], g4[i], s);
            g5[o] = s;   // Linear(16,8): no activation
        }
    }
    float bv = bb6[p];
    {
        const float* W = Wb6 + p * 8;
#pragma unroll
        for (int i = 0; i < 8; ++i) bv = fmaf(W[i], g5[i], bv);
    }

    // ================= Encoder A: 1 ->[64]-> 32 ->[16]-> 8 -> 1 ============
    float h2[32];
    fused2<1, 8, 8, 32, true>(Wa1 + p * 64, ba1 + p * 64,
                              Wa2 + p * (32 * 64), ba2 + p * 32, &xa, h2);
#pragma unroll
    for (int o = 0; o < 32; ++o) h2[o] = fast_tanh(h2[o]);

    float h4[8];
    fused2<32, 2, 8, 8, false>(Wa3 + p * (16 * 32), ba3 + p * 16,
                               Wa4 + p * (8 * 16), ba4 + p * 8, h2, h4);
#pragma unroll
    for (int o = 0; o < 8; ++o) h4[o] = fast_tanh(h4[o]);

    float av = ba5[p];
    {
        const float* W = Wa5 + p * 8;
#pragma unroll
        for (int i = 0; i < 8; ++i) av = fmaf(W[i], h4[i], av);
    }

    // out[n, 2p] = a, out[n, 2p+1] = b  -> one aligned float2 store
    reinterpret_cast<float2*>(out)[n * NP + p] = make_float2(av, bv);
}

extern "C" void kernel_launch(void* const* d_in, const int* in_sizes, int n_in,
                              void* d_out, int out_size, void* d_ws,
                              size_t ws_size, hipStream_t stream) {
    const float* x   = (const float*)d_in[0];
    const float* Wa1 = (const float*)d_in[1];
    const float* ba1 = (const float*)d_in[2];
    const float* Wa2 = (const float*)d_in[3];
    const float* ba2 = (const float*)d_in[4];
    const float* Wa3 = (const float*)d_in[5];
    const float* ba3 = (const float*)d_in[6];
    const float* Wa4 = (const float*)d_in[7];
    const float* ba4 = (const float*)d_in[8];
    const float* Wa5 = (const float*)d_in[9];
    const float* ba5 = (const float*)d_in[10];
    const float* Wb1 = (const float*)d_in[11];
    const float* bb1 = (const float*)d_in[12];
    const float* Wb2 = (const float*)d_in[13];
    const float* bb2 = (const float*)d_in[14];
    const float* Wb3 = (const float*)d_in[15];
    const float* bb3 = (const float*)d_in[16];
    const float* Wb4 = (const float*)d_in[17];
    const float* bb4 = (const float*)d_in[18];
    const float* Wb5 = (const float*)d_in[19];
    const float* bb5 = (const float*)d_in[20];
    const float* Wb6 = (const float*)d_in[21];
    const float* bb6 = (const float*)d_in[22];

    dim3 grid(NROWS / 256, NP);
    fused_mlp<<<grid, 256, 0, stream>>>(
        x, Wa1, ba1, Wa2, ba2, Wa3, ba3, Wa4, ba4, Wa5, ba5,
        Wb1, bb1, Wb2, bb2, Wb3, bb3, Wb4, bb4, Wb5, bb5, Wb6, bb6,
        (float*)d_out);
}